// Round 7
// baseline (22.268 us; speedup 1.0000x reference)
//
#include <hip/hip_runtime.h>

#define NPROTO 20
#define SEQ_LEN 512
#define TPB 256               // 4 waves per block; 2 l-positions per thread

// Correctly-rounded a/d via Markstein refinement, given rc = RN(1/d), nd = -d:
// q0 = RN(a*rc); r = fma(nd,q0,a) (exact); q1 = RN(q0 + r*rc) == RN(a/d).
// Bit-exact vs IEEE divide for this kernel's operand families (verified
// absmax=0 in R3/R4/R6 over the full input set):
//  - d = 3.0f constant
//  - d = integer in [1,510], a = exact integer product < 2^18
__device__ __forceinline__ float div_exact(float a, float nd, float rc)
{
    const float q0 = a * rc;
    const float r  = fmaf(nd, q0, a);
    return fmaf(r, rc, q0);
}

// One block per batch row; 256 threads; thread t covers l = 2t, 2t+1.
// Setup (2 barriers, no serial thread-0 section, no unprotected cross-lane):
//   phase 1: lanes<20 load inputs, compute {m,aL,aR,rc}, stash pi in LDS.
//            barrier.
//   phase 2: every wave-0 lane redundantly computes the sequential mean
//            (bit-exact XLA order) from barrier-protected s_pi; kept lanes
//            ballot-compact their OWN register params into s_c4 in
//            ascending-p order (accumulation order == reference). barrier.
// Main loop: dense nkept iterations, branch-free, sentinel-padded prefetch
// of the single ds_read_b128 so LDS latency overlaps the evals.
__global__ __launch_bounds__(TPB)
void adaptive_mask_kernel(const float* __restrict__ tok,
                          const float* __restrict__ sigma,
                          const float* __restrict__ pi,
                          float* __restrict__ out)
{
    const int b = blockIdx.x;
    const int t = threadIdx.x;

    __shared__ float  s_pi[NPROTO];
    __shared__ float4 s_c4[NPROTO + 1];   // compacted {m,aL,aR,rc}; +1 sentinel
    __shared__ int    s_nkept;

    float m = 0.f, aL = 0.f, aR = 0.f, rc = 0.f, piv = 0.f;
    if (t < NPROTO) {
        const int idx = b * NPROTO + t;
        const float tk = tok[idx];
        const float sg = sigma[idx];
        m  = rintf(fminf(fmaxf(tk, 1.0f), 511.0f));   // round-half-even
        aL = (0.001f * sg) * m;                       // CVL*sigma*m
        aR = (0.001f * sg) * (512.0f - m);            // CVR*sigma*(512-m)
        const float den = (m == 511.0f) ? 1.0f : (511.0f - m);
        rc  = 1.0f / den;                             // IEEE RN(1/den)
        piv = pi[idx];
        s_pi[t] = piv;
    }
    __syncthreads();

    if (t < 64) {   // wave 0 only; all its cross-lane inputs are barrier-protected
        float s = 0.0f;
        #pragma unroll
        for (int p = 0; p < NPROTO; ++p) s += s_pi[p];   // sequential, like XLA
        const float mean = s / 20.0f;                    // identical in every lane
        const bool keep = (t < NPROTO) && (piv >= mean);
        const unsigned long long bal = __ballot(keep);
        if (keep) {
            const int dst = (int)__popcll(bal & ((1ull << t) - 1ull));
            s_c4[dst] = make_float4(m, aL, aR, rc);      // own registers -> LDS
        }
        if (t == 0) s_nkept = (int)__popcll(bal);
    }
    __syncthreads();

    const int nkept = __builtin_amdgcn_readfirstlane(s_nkept);
    const float C3 = 1.0f / 3.0f;      // RN(1/3)

    const float lf0 = (float)(2 * t);
    const float lf1 = lf0 + 1.0f;      // exact
    float acc0 = 0.f, acc1 = 0.f;

    float4 P = s_c4[0];
    #pragma unroll 1
    for (int p = 0; p < nkept; ++p) {
        const float4 Pn = s_c4[p + 1];   // prefetch; sentinel slot makes it safe
        const float mm = P.x, vaL = P.y, vaR = P.z, vrc = P.w;
        const float msub = mm - 512.0f;                              // exact
        const float nden = (mm == 511.0f) ? -1.0f : (mm - 511.0f);   // -den, exact

#define EVAL(LF, ACC)                                                       \
        {                                                                   \
            const float q    = (LF) - mm;                                   \
            const float num  = q * msub;            /* exact int product */ \
            const float rq   = div_exact(num, nden, vrc); /* RN(num/den) */ \
            const float left = (q + 1.0f) + vaL;                            \
            const float rt   = (-1.0f + rq) + vaR;                          \
            const float base = ((LF) < mm) ? left : rt;                     \
            (ACC) += div_exact(base, -3.0f, C3) + 1.0f;                     \
        }

        EVAL(lf0, acc0)
        EVAL(lf1, acc1)
#undef EVAL
        P = Pn;
    }

    float2 res;
    res.x = (acc0 > 0.0f) ? 1.0f : 0.0f;
    res.y = (acc1 > 0.0f) ? 1.0f : 0.0f;
    *reinterpret_cast<float2*>(out + (size_t)b * SEQ_LEN + 2 * t) = res;
}

extern "C" void kernel_launch(void* const* d_in, const int* in_sizes, int n_in,
                              void* d_out, int out_size, void* d_ws, size_t ws_size,
                              hipStream_t stream)
{
    const float* tok   = (const float*)d_in[0];
    const float* sigma = (const float*)d_in[1];
    const float* pi    = (const float*)d_in[2];
    float* out = (float*)d_out;

    const int B = in_sizes[0] / NPROTO;   // 8192
    adaptive_mask_kernel<<<B, TPB, 0, stream>>>(tok, sigma, pi, out);
}